// Round 5
// baseline (351.065 us; speedup 1.0000x reference)
//
#include <hip/hip_runtime.h>
#include <stdint.h>

#define B_ 64
#define T_ 2048
#define D_ 256
#define U_ 256
#define BT 256            // T rows per score_ctx block
#define NT (BT / 16)      // 16 tiles of 16 rows
#define TC (T_ / BT)      // 8 chunks per batch
#define SHIFT_ 8.0f       // fixed softmax shift; |score| <= sum|V_w| ~ 10 -> exp(s-8) fp32-safe

typedef _Float16 half8   __attribute__((ext_vector_type(8)));
typedef _Float16 halfx4  __attribute__((ext_vector_type(4)));
typedef float    floatx4 __attribute__((ext_vector_type(4)));

// ---------------- Kernel 1 (merged): qproj (blocks 0..63) + w2t (blocks 64..127) ----------
__global__ void prep_kernel(const float* __restrict__ query,
                            const float* __restrict__ W1_w,
                            const float* __restrict__ W1_b,
                            const float* __restrict__ W2_b,
                            const float* __restrict__ W2_w,
                            float* __restrict__ qb,
                            _Float16* __restrict__ w2t) {
    __shared__ float qrow[D_];
    __shared__ float tile[32][33];
    if (blockIdx.x < 64) {
        // qb[b,u] = query[b]·W1[:,u] + W1_b[u] + W2_b[u]
        const int b = blockIdx.x;
        const int u = threadIdx.x;           // 256 == U_
        qrow[u] = query[b * D_ + u];
        __syncthreads();
        float a0 = 0.f, a1 = 0.f, a2 = 0.f, a3 = 0.f;
#pragma unroll 4
        for (int d = 0; d < D_; d += 4) {
            a0 += qrow[d    ] * W1_w[(d    ) * U_ + u];
            a1 += qrow[d + 1] * W1_w[(d + 1) * U_ + u];
            a2 += qrow[d + 2] * W1_w[(d + 2) * U_ + u];
            a3 += qrow[d + 3] * W1_w[(d + 3) * U_ + u];
        }
        qb[b * U_ + u] = (a0 + a1) + (a2 + a3) + W1_b[u] + W2_b[u];
    } else {
        // w2t[u,d] = (fp16) W2[d,u]
        const int bid = blockIdx.x - 64;
        const int tu = bid & 7;              // u tile
        const int td = bid >> 3;             // d tile
        const int c  = threadIdx.x & 31;
        const int r0 = threadIdx.x >> 5;     // 0..7
#pragma unroll
        for (int i = 0; i < 4; ++i) {
            int r = r0 + i * 8;
            tile[r][c] = W2_w[(td * 32 + r) * U_ + tu * 32 + c];
        }
        __syncthreads();
#pragma unroll
        for (int i = 0; i < 4; ++i) {
            int r = r0 + i * 8;              // u within tile
            w2t[(tu * 32 + r) * D_ + td * 32 + c] = (_Float16)tile[c][r];
        }
    }
}

// ---------------- Kernel 2 (fused): scores + fixed-shift partial softmax context ----------------
// Grid (TC=8, B)=512 blocks of 512 threads (8 waves) -> 2 blocks/CU, 16 waves/CU = 4 waves/SIMD.
// amdgpu_waves_per_eu(4,4): PIN the register budget to exactly 128 VGPR/lane. R3/R4 lesson:
// __launch_bounds__(.., 4) sets only a MIN waves/EU; LLVM's occupancy heuristic tier-jumped to
// 8 waves/EU (64-VGPR budget) and spilled ~45 regs/lane -> 465 MB of scratch FETCH. Pinning
// min=max=4 removes the incentive; live set ~110 regs fits 128 with zero spill.
// Wave w owns U-chunk [w*32, w*32+32): bfrag[2][8] = 64 VGPR. Values reg-staged to fp16 LDS
// (double-buffered 8KB tiles, depth-2): global fp32 -> regs (issued 1 tile early) -> cvt fp16
// -> ds_write_b64, XOR-swizzled: 16B chunk (r, cc) at chunk cc^(r&7). MFMA A = one
// ds_read_b128 per K-slice, zero cvt. Barriers lgkm-only (staged loads fly across them).
// Phase 2 splits 16 rows across thread halves (h = tid>>8); halves combined once at the end.
__launch_bounds__(512)
__attribute__((amdgpu_waves_per_eu(4, 4)))
__global__ void score_ctx_kernel(const float* __restrict__ values,
                                 const _Float16* __restrict__ w2t,
                                 const float* __restrict__ qb,
                                 const float* __restrict__ V_w,
                                 float* __restrict__ scores,
                                 float* __restrict__ pctx,
                                 float* __restrict__ pl) {
    __shared__ __align__(16) _Float16 buf[2][16 * D_];  // 2 x 8KB fp16 tiles
    __shared__ __align__(16) float s_part2[16][8];      // [row t][wave] partial scores
    __shared__ float sbuf[BT];                          // raw scores for this chunk
    __shared__ float cbuf[D_];                          // half-1 context partials
    __shared__ float lbuf[2];

    const int b     = blockIdx.y;
    const int chunk = blockIdx.x;
    const int tid   = threadIdx.x;
    const int wave  = tid >> 6;          // 0..7
    const int lane  = tid & 63;
    const int n16   = lane & 15;
    const int quad  = lane >> 4;
    const int h     = tid >> 8;          // row-half for phase 2
    const int d     = tid & 255;         // context dim owned

    // --- W2 B-fragments, register-stationary: u-chunk 32 per wave (verified layout) ---
    half8 bfrag[2][8];
#pragma unroll
    for (int ut = 0; ut < 2; ++ut) {
        const int u = wave * 32 + ut * 16 + n16;
#pragma unroll
        for (int k = 0; k < 8; ++k)
            bfrag[ut][k] = *(const half8*)(w2t + u * D_ + k * 32 + quad * 8);
    }
    float qbv[2], vwv[2];
#pragma unroll
    for (int ut = 0; ut < 2; ++ut) {
        const int u = wave * 32 + ut * 16 + n16;
        qbv[ut] = qb[b * U_ + u];
        vwv[ut] = V_w[u];
    }

    const float* vbase = values + (size_t)b * T_ * D_ + (size_t)chunk * BT * D_;

    // MFMA A addressing: K-slice k, lane (n16, quad) needs 16B chunk (k*4+quad) of row n16;
    // swizzled chunk = (k*4+quad) ^ (n16&7). With s3=n16&3, sb2=bit2:
    // byte = n16*512 + (quad^s3)*16 + ((k&1)^sb2)*64 + (k>>1)*128 -> bases A0 (k even), A1 (k odd).
    const int s3  = n16 & 3;
    const int sb2 = (n16 >> 2) & 1;
    const int abase = n16 * 512 + ((quad ^ s3) << 4);
    const int A0 = abase + (sb2 ? 64 : 0);
    const int A1 = abase + (sb2 ? 0 : 64);

    // Context mapping for dim d: fp16 chunk cc=d>>3, byte (d&7)*2; row r: byte =
    // r*512 + (ob0 ^ ((r&7)<<4)), ob0 = (cc<<4) + (d&7)*2.
    const int ob0 = ((d >> 3) << 4) + (d & 7) * 2;

    // Staging: wave stages rows {wave, wave+8} of each tile; lane owns fp32 16B chunk 'lane'
    // of the row (1KB contiguous per wave -> coalesced). Both rows have (r&7)==wave, so one
    // swizzled write offset: wOff = wave*512 + (((lane>>1)^wave)<<4) + (lane&1)*8.
    const int wOff = wave * 512 + ((((lane >> 1) ^ wave) & 31) << 4) + (lane & 1) * 8;

    float c = 0.f;    // context accumulator: dim d, rows of half h
    float l = 0.f;    // sum of exp(s - SHIFT_) over rows of half h

    floatx4 st0, st1;   // staged fp32 (one tile in flight)

    auto loadst = [&](int t) {
        const float* p = vbase + (size_t)(t * 16 + wave) * D_ + lane * 4;
        st0 = *(const floatx4*)(p);
        st1 = *(const floatx4*)(p + 8 * D_);
    };
    auto writest = [&](int bi) {
        char* dstb = (char*)&buf[bi][0];
        halfx4 hh;
        hh[0] = (_Float16)st0.x; hh[1] = (_Float16)st0.y; hh[2] = (_Float16)st0.z; hh[3] = (_Float16)st0.w;
        *(halfx4*)(dstb + wOff) = hh;                 // row 'wave'
        hh[0] = (_Float16)st1.x; hh[1] = (_Float16)st1.y; hh[2] = (_Float16)st1.z; hh[3] = (_Float16)st1.w;
        *(halfx4*)(dstb + wOff + 8 * 512) = hh;       // row 'wave+8'
    };

    // prologue: tile0 -> slot0; tile1 loads in flight
    loadst(0);
    writest(0);
    loadst(1);

#pragma unroll 1
    for (int tile = 0; tile < NT; ++tile) {
        const int cur = tile & 1;
        // B1: this slot's ds_writes + prior phase-2 reads done. lgkm-only: staged
        // global loads stay in flight across the barrier.
        asm volatile("s_waitcnt lgkmcnt(0)" ::: "memory");
        __builtin_amdgcn_s_barrier();
        asm volatile("" ::: "memory");

        // --- phase 1: MFMA Vp[16 rows x 32u], A direct from fp16 LDS (no cvt) ---
        const char* slotp = (const char*)&buf[cur][0];
        floatx4 acc[2] = {};
#pragma unroll
        for (int m = 0; m < 4; ++m) {
            half8 a0 = *(const half8*)(slotp + A0 + m * 128);   // K-slice 2m
            half8 a1 = *(const half8*)(slotp + A1 + m * 128);   // K-slice 2m+1
            acc[0] = __builtin_amdgcn_mfma_f32_16x16x32_f16(a0, bfrag[0][2 * m], acc[0], 0, 0, 0);
            acc[1] = __builtin_amdgcn_mfma_f32_16x16x32_f16(a0, bfrag[1][2 * m], acc[1], 0, 0, 0);
            acc[0] = __builtin_amdgcn_mfma_f32_16x16x32_f16(a1, bfrag[0][2 * m + 1], acc[0], 0, 0, 0);
            acc[1] = __builtin_amdgcn_mfma_f32_16x16x32_f16(a1, bfrag[1][2 * m + 1], acc[1], 0, 0, 0);
        }

        // --- epilogue: tanh + dot with V_w, reduce over u (n16) ---
        float part[4];
#pragma unroll
        for (int r = 0; r < 4; ++r) {
            float sa = 0.f;
#pragma unroll
            for (int ut = 0; ut < 2; ++ut) {
                float x  = acc[ut][r] + qbv[ut];
                float e  = __expf(2.f * x);
                float th = 1.f - __fdividef(2.f, e + 1.f);   // tanh(x)
                sa += th * vwv[ut];
            }
            part[r] = sa;
        }
#pragma unroll
        for (int m = 1; m < 16; m <<= 1)
#pragma unroll
            for (int r = 0; r < 4; ++r)
                part[r] += __shfl_xor(part[r], m, 16);
        if (n16 == 0) {
#pragma unroll
            for (int r = 0; r < 4; ++r)
                s_part2[quad * 4 + r][wave] = part[r];       // row t = quad*4+r
        }

        // B2: s_part2 visible (lgkm-only)
        asm volatile("s_waitcnt lgkmcnt(0)" ::: "memory");
        __builtin_amdgcn_s_barrier();
        asm volatile("" ::: "memory");

        // --- staging: write tile+1 into other slot (nobody reads it this tile),
        //     then issue loads for tile+2 (stay in flight across next barriers) ---
        if (tile + 1 < NT) writest(cur ^ 1);
        if (tile + 2 < NT) loadst(tile + 2);

        // --- phase 2: half h handles rows h*8..h*8+7 -> weights + context FMA ---
        const float* sp2 = &s_part2[0][0];
        const char* hbase = slotp + h * 8 * 512;
        const float* sph  = sp2 + h * 8 * 8;
#pragma unroll
        for (int t = 0; t < 8; ++t) {
            floatx4 spA = *(const floatx4*)(sph + t * 8);     // wave-uniform -> broadcast
            floatx4 spB = *(const floatx4*)(sph + t * 8 + 4);
            float sv = ((spA.x + spA.y) + (spA.z + spA.w)) + ((spB.x + spB.y) + (spB.z + spB.w));
            float w  = __expf(sv - SHIFT_);
            l += w;
            float v = (float)*(const _Float16*)(hbase + t * 512 + (ob0 ^ (t << 4)));
            c += w * v;                                       // v_fma_mix
        }
        if (tid < 16) {
            floatx4 spA = *(const floatx4*)(sp2 + tid * 8);
            floatx4 spB = *(const floatx4*)(sp2 + tid * 8 + 4);
            sbuf[tile * 16 + tid] = ((spA.x + spA.y) + (spA.z + spA.w)) + ((spB.x + spB.y) + (spB.z + spB.w));
        }
    }

    // --- combine the two row-halves, write partials ---
    if (h == 1) {
        cbuf[d] = c;
        if (tid == 256) lbuf[1] = l;
    }
    __syncthreads();
    if (h == 0) pctx[(b * TC + chunk) * D_ + d] = c + cbuf[d];
    if (tid < BT) scores[b * T_ + chunk * BT + tid] = sbuf[tid];
    if (tid == 0) pl[b * TC + chunk] = l + lbuf[1];
}

// ---------------- Kernel 3: combine partials -> ctx, attn ----------------
__global__ void finalize_kernel(const float* __restrict__ pctx,
                                const float* __restrict__ pl,
                                const float* __restrict__ scores,
                                float* __restrict__ ctx,
                                float* __restrict__ attn) {
    const int b = blockIdx.x, tid = threadIdx.x;   // 256 threads
    float L = 0.f;
#pragma unroll
    for (int i = 0; i < TC; ++i) L += pl[b * TC + i];
    float s = 0.f;
#pragma unroll
    for (int i = 0; i < TC; ++i) s += pctx[(b * TC + i) * D_ + tid];
    const float invL = __fdividef(1.f, L);
    ctx[b * D_ + tid] = s * invL;
#pragma unroll
    for (int j = 0; j < T_ / 256; ++j) {
        const int t = j * 256 + tid;
        attn[b * T_ + t] = __expf(scores[b * T_ + t] - SHIFT_) * invL;
    }
}

extern "C" void kernel_launch(void* const* d_in, const int* in_sizes, int n_in,
                              void* d_out, int out_size, void* d_ws, size_t ws_size,
                              hipStream_t stream) {
    const float* query  = (const float*)d_in[0];
    const float* values = (const float*)d_in[1];
    const float* W1_w   = (const float*)d_in[2];
    const float* W1_b   = (const float*)d_in[3];
    const float* W2_w   = (const float*)d_in[4];
    const float* W2_b   = (const float*)d_in[5];
    const float* V_w    = (const float*)d_in[6];
    // d_in[7] = V_b: softmax is shift-invariant -> no effect on either output.

    float* out  = (float*)d_out;
    float* ctx  = out;                  // [B, D]
    float* attn = out + B_ * D_;        // [B, T]

    char* ws = (char*)d_ws;
    float*    qb     = (float*)ws;                               // B*U fp32       (64 KB)
    _Float16* w2t    = (_Float16*)(ws + (64 << 10));             // U*D fp16       (128 KB)
    float*    scores = (float*)(ws + (192 << 10));               // B*T fp32       (512 KB)
    float*    pctx   = (float*)(ws + (704 << 10));               // B*TC*D fp32    (512 KB)
    float*    pl     = (float*)(ws + (1216 << 10));              // B*TC fp32      (2 KB)

    prep_kernel     <<<dim3(128),     dim3(256), 0, stream>>>(query, W1_w, W1_b, W2_b, W2_w, qb, w2t);
    score_ctx_kernel<<<dim3(TC, B_),  dim3(512), 0, stream>>>(values, w2t, qb, V_w, scores, pctx, pl);
    finalize_kernel <<<dim3(B_),      dim3(256), 0, stream>>>(pctx, pl, scores, ctx, attn);
}

// Round 6
// 239.983 us; speedup vs baseline: 1.4629x; 1.4629x over previous
//
#include <hip/hip_runtime.h>
#include <stdint.h>

#define B_ 64
#define T_ 2048
#define D_ 256
#define U_ 256
#define BT 128            // T rows per score_ctx block
#define NT (BT / 16)      // 8 tiles of 16 rows
#define TC (T_ / BT)      // 16 chunks per batch
#define SHIFT_ 8.0f       // fixed softmax shift; |score| <= sum|V_w| ~ 10 -> exp(s-8) fp32-safe

typedef _Float16 half8   __attribute__((ext_vector_type(8)));
typedef float    floatx4 __attribute__((ext_vector_type(4)));

typedef const __attribute__((address_space(1))) void cg_void;   // global src for DMA
typedef __attribute__((address_space(3))) void       ls_void;   // LDS dst for DMA

// ---------------- Kernel 1 (merged): qproj (blocks 0..63) + w2t (blocks 64..127) ----------
__global__ void prep_kernel(const float* __restrict__ query,
                            const float* __restrict__ W1_w,
                            const float* __restrict__ W1_b,
                            const float* __restrict__ W2_b,
                            const float* __restrict__ W2_w,
                            float* __restrict__ qb,
                            _Float16* __restrict__ w2t) {
    __shared__ float qrow[D_];
    __shared__ float tile[32][33];
    if (blockIdx.x < 64) {
        // qb[b,u] = query[b]·W1[:,u] + W1_b[u] + W2_b[u]
        const int b = blockIdx.x;
        const int u = threadIdx.x;           // 256 == U_
        qrow[u] = query[b * D_ + u];
        __syncthreads();
        float a0 = 0.f, a1 = 0.f, a2 = 0.f, a3 = 0.f;
#pragma unroll 4
        for (int d = 0; d < D_; d += 4) {
            a0 += qrow[d    ] * W1_w[(d    ) * U_ + u];
            a1 += qrow[d + 1] * W1_w[(d + 1) * U_ + u];
            a2 += qrow[d + 2] * W1_w[(d + 2) * U_ + u];
            a3 += qrow[d + 3] * W1_w[(d + 3) * U_ + u];
        }
        qb[b * U_ + u] = (a0 + a1) + (a2 + a3) + W1_b[u] + W2_b[u];
    } else {
        // w2t[u,d] = (fp16) W2[d,u]
        const int bid = blockIdx.x - 64;
        const int tu = bid & 7;              // u tile
        const int td = bid >> 3;             // d tile
        const int c  = threadIdx.x & 31;
        const int r0 = threadIdx.x >> 5;     // 0..7
#pragma unroll
        for (int i = 0; i < 4; ++i) {
            int r = r0 + i * 8;
            tile[r][c] = W2_w[(td * 32 + r) * U_ + tu * 32 + c];
        }
        __syncthreads();
#pragma unroll
        for (int i = 0; i < 4; ++i) {
            int r = r0 + i * 8;              // u within tile
            w2t[(tu * 32 + r) * D_ + td * 32 + c] = (_Float16)tile[c][r];
        }
    }
}

// ---------------- Kernel 2 (fused): scores + fixed-shift partial softmax context ----------------
// R2-proven register structure (256 thr / 4 waves / bfrag[4][8] / launch_bounds(256,2) ->
// VGPR=128, ZERO spill), residency raised by the GRID: BT=128 -> (16,64)=1024 blocks =
// 4 blocks/CU; LDS cut to ~33KB (2-slot double buffer) so 4 blocks fit (132KB<160KB);
// 128 VGPR allows 4 waves/SIMD -> 16 waves/CU, 2x R2's residency. R3/R4/R5 lesson: any
// 512-thread variant spills (backend pins 64-VGPR tier); do NOT touch the block shape.
// fp32 value tiles staged via global_load_lds(16B) into XOR-swizzled LDS
// (16B chunk (row,cc) at chunk row*64 + (cc ^ (row&7))); per-tile vmcnt(0) drain is issued
// a full tile after the loads and covered by the other 3 resident blocks' waves.
__launch_bounds__(256, 2)
__global__ void score_ctx_kernel(const float* __restrict__ values,
                                 const _Float16* __restrict__ w2t,
                                 const float* __restrict__ qb,
                                 const float* __restrict__ V_w,
                                 float* __restrict__ scores,
                                 float* __restrict__ pctx,
                                 float* __restrict__ pl) {
    __shared__ __align__(16) float buf[2][16 * D_];    // 2 x 16KB fp32 tiles
    __shared__ __align__(16) float s_part2[16][4];     // [row t][wave] partial scores
    __shared__ float sbuf[BT];                          // raw scores for this chunk

    const int b     = blockIdx.y;
    const int chunk = blockIdx.x;
    const int tid   = threadIdx.x;
    const int wave  = tid >> 6;
    const int lane  = tid & 63;
    const int n16   = lane & 15;
    const int quad  = lane >> 4;
    const int u0    = wave * 64;

    // --- W2 B-fragments, register-stationary (verified layout) ---
    half8 bfrag[4][8];
#pragma unroll
    for (int ut = 0; ut < 4; ++ut) {
        const int u = u0 + ut * 16 + n16;
#pragma unroll
        for (int k = 0; k < 8; ++k)
            bfrag[ut][k] = *(const half8*)(w2t + u * D_ + k * 32 + quad * 8);
    }
    float qbv[4], vwv[4];
#pragma unroll
    for (int ut = 0; ut < 4; ++ut) {
        const int u = u0 + ut * 16 + n16;
        qbv[ut] = qb[b * U_ + u];
        vwv[ut] = V_w[u];
    }

    const float* vbase = values + (size_t)b * T_ * D_ + (size_t)chunk * BT * D_;

    // MFMA A-operand: global chunk c0=k*8+quad*2 lives at LDS chunk k*8 + ((quad*2)^swz)
    // since swz<8. Hoisted per-lane bases; k-loop strides 8 chunks = 32 floats (k<<5).
    const int e0 = (quad * 2) ^ (n16 & 7);
    const int e1 = e0 ^ 1;

    // Context mapping for d = tid: global chunk g=tid>>2 at LDS chunk g^(row&7).
    const int g = tid >> 2, lo = tid & 3;
    int co[8];
#pragma unroll
    for (int s = 0; s < 8; ++s) co[s] = (((g ^ s) & 63) << 2) + lo;

    float c = 0.f;    // context accumulator: this thread owns d = tid
    float l = 0.f;    // sum of exp(s - SHIFT_) (identical in all threads)

    // stage one 16-row tile: 16 wave-level DMA ops, 4 per wave (wave-uniform LDS base)
    auto stage = [&](int tile, int bi) {
        const float* src = vbase + tile * 16 * D_;
#pragma unroll
        for (int i = 0; i < 4; ++i) {
            const int r = i * 4 + wave;                          // wave-uniform row
            const float* gp = src + r * D_ + ((lane ^ (r & 7)) << 2);
            float* lp = &buf[bi][r * D_];
            __builtin_amdgcn_global_load_lds((cg_void*)gp, (ls_void*)lp, 16, 0, 0);
        }
    };

    stage(0, 0);

#pragma unroll 1
    for (int tile = 0; tile < NT; ++tile) {
        const int cur = tile & 1;
        // B1: tile 'cur' staged (drain own DMA) + all waves past phase-2 of tile-1.
        asm volatile("s_waitcnt vmcnt(0) lgkmcnt(0)" ::: "memory");
        __builtin_amdgcn_s_barrier();
        asm volatile("" ::: "memory");

        // prefetch tile+1 into the other slot (its last readers passed B1 above);
        // these 4 loads stay in flight through this whole tile's compute.
        if (tile + 1 < NT) stage(tile + 1, cur ^ 1);

        // --- phase 1: MFMA Vp[16 x 64chunk], A from swizzled fp32 LDS, cvt in regs ---
        const float* a0p = &buf[cur][n16 * D_] + (e0 << 2);
        const float* a1p = &buf[cur][n16 * D_] + (e1 << 2);
        floatx4 acc[4] = {};
#pragma unroll
        for (int k = 0; k < 8; ++k) {
            floatx4 q0 = *(const floatx4*)(a0p + (k << 5));   // k*8 chunks = 128B imm offset
            floatx4 q1 = *(const floatx4*)(a1p + (k << 5));
            half8 a;
            a[0] = (_Float16)q0.x; a[1] = (_Float16)q0.y;
            a[2] = (_Float16)q0.z; a[3] = (_Float16)q0.w;
            a[4] = (_Float16)q1.x; a[5] = (_Float16)q1.y;
            a[6] = (_Float16)q1.z; a[7] = (_Float16)q1.w;
#pragma unroll
            for (int ut = 0; ut < 4; ++ut)
                acc[ut] = __builtin_amdgcn_mfma_f32_16x16x32_f16(a, bfrag[ut][k], acc[ut], 0, 0, 0);
        }

        // --- epilogue: tanh + dot with V_w, reduce over u (n16) ---
        float part[4];
#pragma unroll
        for (int r = 0; r < 4; ++r) {
            float sa = 0.f;
#pragma unroll
            for (int ut = 0; ut < 4; ++ut) {
                float x  = acc[ut][r] + qbv[ut];
                float e  = __expf(2.f * x);
                float th = 1.f - __fdividef(2.f, e + 1.f);   // tanh(x)
                sa += th * vwv[ut];
            }
            part[r] = sa;
        }
#pragma unroll
        for (int m = 1; m < 16; m <<= 1)
#pragma unroll
            for (int r = 0; r < 4; ++r)
                part[r] += __shfl_xor(part[r], m, 16);
        if (n16 == 0) {
#pragma unroll
            for (int r = 0; r < 4; ++r)
                s_part2[quad * 4 + r][wave] = part[r];       // row t = quad*4+r
        }

        // B2: s_part2 visible (lgkm-only; prefetch DMA stays in flight)
        asm volatile("s_waitcnt lgkmcnt(0)" ::: "memory");
        __builtin_amdgcn_s_barrier();
        asm volatile("" ::: "memory");

        // --- phase 2: every thread computes the 16 weights + context FMA ---
        const float* bufp = &buf[cur][0];
        const float* sp2  = &s_part2[0][0];
#pragma unroll
        for (int t = 0; t < 16; ++t) {
            floatx4 sp = *(const floatx4*)(sp2 + t * 4);     // wave-uniform -> broadcast
            float sv = (sp.x + sp.y) + (sp.z + sp.w);
            float w  = __expf(sv - SHIFT_);
            l += w;
            c += w * bufp[t * D_ + co[t & 7]];               // imm offset t*1024B
        }
        if (tid < 16) {
            floatx4 sp = *(const floatx4*)(sp2 + tid * 4);
            sbuf[tile * 16 + tid] = (sp.x + sp.y) + (sp.z + sp.w);
        }
    }

    __syncthreads();   // sbuf visible
    pctx[(b * TC + chunk) * D_ + tid] = c;
    if (tid < BT) scores[b * T_ + chunk * BT + tid] = sbuf[tid];
    if (tid == 0) pl[b * TC + chunk] = l;
}

// ---------------- Kernel 3: combine partials -> ctx, attn ----------------
__global__ void finalize_kernel(const float* __restrict__ pctx,
                                const float* __restrict__ pl,
                                const float* __restrict__ scores,
                                float* __restrict__ ctx,
                                float* __restrict__ attn) {
    const int b = blockIdx.x, tid = threadIdx.x;   // 256 threads
    float L = 0.f;
#pragma unroll
    for (int i = 0; i < TC; ++i) L += pl[b * TC + i];
    float s = 0.f;
#pragma unroll
    for (int i = 0; i < TC; ++i) s += pctx[(b * TC + i) * D_ + tid];
    const float invL = __fdividef(1.f, L);
    ctx[b * D_ + tid] = s * invL;
#pragma unroll
    for (int j = 0; j < T_ / 256; ++j) {
        const int t = j * 256 + tid;
        attn[b * T_ + t] = __expf(scores[b * T_ + t] - SHIFT_) * invL;
    }
}

extern "C" void kernel_launch(void* const* d_in, const int* in_sizes, int n_in,
                              void* d_out, int out_size, void* d_ws, size_t ws_size,
                              hipStream_t stream) {
    const float* query  = (const float*)d_in[0];
    const float* values = (const float*)d_in[1];
    const float* W1_w   = (const float*)d_in[2];
    const float* W1_b   = (const float*)d_in[3];
    const float* W2_w   = (const float*)d_in[4];
    const float* W2_b   = (const float*)d_in[5];
    const float* V_w    = (const float*)d_in[6];
    // d_in[7] = V_b: softmax is shift-invariant -> no effect on either output.

    float* out  = (float*)d_out;
    float* ctx  = out;                  // [B, D]
    float* attn = out + B_ * D_;        // [B, T]

    char* ws = (char*)d_ws;
    float*    qb     = (float*)ws;                               // B*U fp32       (64 KB)
    _Float16* w2t    = (_Float16*)(ws + (64 << 10));             // U*D fp16       (128 KB)
    float*    scores = (float*)(ws + (192 << 10));               // B*T fp32       (512 KB)
    float*    pctx   = (float*)(ws + (704 << 10));               // B*TC*D fp32    (1 MB)
    float*    pl     = (float*)(ws + (1728 << 10));              // B*TC fp32      (4 KB)

    prep_kernel     <<<dim3(128),     dim3(256), 0, stream>>>(query, W1_w, W1_b, W2_b, W2_w, qb, w2t);
    score_ctx_kernel<<<dim3(TC, B_),  dim3(256), 0, stream>>>(values, w2t, qb, V_w, scores, pctx, pl);
    finalize_kernel <<<dim3(B_),      dim3(256), 0, stream>>>(pctx, pl, scores, ctx, attn);
}